// Round 1
// baseline (859.828 us; speedup 1.0000x reference)
//
#include <hip/hip_runtime.h>
#include <stdint.h>

// Problem constants
#define M_TOT 147456   // B*P = 16*9216
#define KD    768      // D
#define HN    768      // H
#define PP    9216
#define BM    64
#define BK    64
#define NSTEP 12       // 768/64
#define THREADS 768    // 12 waves

typedef __attribute__((ext_vector_type(4)))  int i32x4;
typedef __attribute__((ext_vector_type(16))) int i32x16;

// ---------------------------------------------------------------------------
// async global->LDS 16B
__device__ __forceinline__ void gload_lds16(const void* gsrc, void* ldst) {
  __builtin_amdgcn_global_load_lds(
      (const __attribute__((address_space(1))) void*)gsrc,
      (__attribute__((address_space(3))) void*)ldst, 16, 0, 0);
}

// ---------------------------------------------------------------------------
// Kernel 0: max |W| -> ws[0] (uint bits; valid compare for non-negative floats)
__global__ void wmax_kernel(const float* __restrict__ w, uint32_t* __restrict__ wmax) {
  int i = blockIdx.x * blockDim.x + threadIdx.x;
  const float4* w4 = (const float4*)w;
  const int n4 = (HN * KD) / 4;           // 147456
  float m = 0.0f;
  for (int j = i; j < n4; j += gridDim.x * blockDim.x) {
    float4 v = w4[j];
    m = fmaxf(m, fmaxf(fmaxf(fabsf(v.x), fabsf(v.y)), fmaxf(fabsf(v.z), fabsf(v.w))));
  }
  for (int off = 32; off; off >>= 1) m = fmaxf(m, __shfl_xor(m, off, 64));
  if ((threadIdx.x & 63) == 0) atomicMax(wmax, __float_as_uint(m));
}

// ---------------------------------------------------------------------------
// Kernel 1: quantize W -> int8, stored PRE-SWIZZLED as 12 contiguous LDS images.
// Image for k-step s: [h][kb] bytes (row stride 64) where byte (h, kb) holds
// W_q[h][ s*64 + (chunk(kb) ^ ((h>>1)&3))*16 + (kb&15) ].
// Then the GEMM stages it with a LINEAR global_load_lds copy.
__global__ void wq_kernel(const float* __restrict__ w,
                          const uint32_t* __restrict__ wmaxbits,
                          int32_t* __restrict__ wq) {
  int gid = blockIdx.x * blockDim.x + threadIdx.x;   // one int32 (4 bytes) each
  const int ntot = (HN * KD) / 4;
  if (gid >= ntot) return;
  float s = __uint_as_float(*wmaxbits) / 127.0f;
  int o    = gid * 4;
  int step = o / (HN * BK);
  int rem  = o - step * (HN * BK);
  int h    = rem >> 6;
  int kb   = rem & 63;
  int chunk = (kb >> 4) ^ ((h >> 1) & 3);
  int k    = step * 64 + chunk * 16 + (kb & 15);     // kb&15 is multiple of 4
  float4 v = *(const float4*)(w + h * KD + k);
  int q0 = (int)rintf(v.x / s); q0 = q0 < -128 ? -128 : (q0 > 127 ? 127 : q0);
  int q1 = (int)rintf(v.y / s); q1 = q1 < -128 ? -128 : (q1 > 127 ? 127 : q1);
  int q2 = (int)rintf(v.z / s); q2 = q2 < -128 ? -128 : (q2 > 127 ? 127 : q2);
  int q3 = (int)rintf(v.w / s); q3 = q3 < -128 ? -128 : (q3 > 127 ? 127 : q3);
  uint32_t packed = ((uint32_t)q0 & 0xff) | (((uint32_t)q1 & 0xff) << 8) |
                    (((uint32_t)q2 & 0xff) << 16) | (((uint32_t)q3 & 0xff) << 24);
  wq[gid] = (int32_t)packed;
}

// ---------------------------------------------------------------------------
// Kernel 2: main fused GEMM.
// Block: 64 rows (one M-tile) x full H=768. 12 waves, wave tile 64x64
// (2x2 of 32x32x32 i8 MFMA). Double-buffered LDS, one barrier per K-step.
__global__ __launch_bounds__(THREADS, 3) void gemm_kernel(
    const float* __restrict__ X, const int8_t* __restrict__ Wq,
    const uint32_t* __restrict__ wmaxbits, const float* __restrict__ pos,
    float* __restrict__ out) {
  __shared__ __align__(16) signed char As[2][BM * BK];      // 2 x 4 KB
  __shared__ __align__(16) signed char Bs[2][HN * BK];      // 2 x 48 KB

  const int tid  = threadIdx.x;
  const int lane = tid & 63;
  const int wv   = tid >> 6;          // 0..11, owns cols [wv*64, wv*64+64)
  const int m0   = blockIdx.x * BM;

  i32x16 acc[2][2];
#pragma unroll
  for (int mi = 0; mi < 2; ++mi)
#pragma unroll
    for (int ni = 0; ni < 2; ++ni)
#pragma unroll
      for (int r = 0; r < 16; ++r) acc[mi][ni][r] = 0;

  // A staging role: threads 0..511, 8 fp32 each (row = tid>>3, col8 = (tid&7)*8)
  const int ar_row = tid >> 3;
  const int ar_c8  = (tid & 7) * 8;
  const float* xrow = X + (m0 + ar_row) * KD + ar_c8;

  const int rr = lane & 31;
  const int kh = lane >> 5;

  float4 av0, av1;

  // ---- prologue: stage t=0 ----
  if (tid < 512) {
    av0 = *(const float4*)(xrow + 0 * BK);
    av1 = *(const float4*)(xrow + 0 * BK + 4);
  }
#pragma unroll
  for (int i = 0; i < 4; ++i)
    gload_lds16(Wq + 0 * (HN * BK) + i * 12288 + tid * 16,
                &Bs[0][i * 12288 + wv * 1024]);
  if (tid < 512) {
    float f[8] = {av0.x, av0.y, av0.z, av0.w, av1.x, av1.y, av1.z, av1.w};
    uint32_t b[8];
#pragma unroll
    for (int j = 0; j < 8; ++j) {
      int q = (int)rintf((f[j] - 0.5f) * 254.0f);
      q = q < -128 ? -128 : (q > 127 ? 127 : q);
      b[j] = (uint32_t)q & 0xff;
    }
    uint2 uv;
    uv.x = b[0] | (b[1] << 8) | (b[2] << 16) | (b[3] << 24);
    uv.y = b[4] | (b[5] << 8) | (b[6] << 16) | (b[7] << 24);
    int chunk = (ar_c8 >> 4) ^ ((ar_row >> 1) & 3);
    *(uint2*)(&As[0][ar_row * 64 + chunk * 16 + (ar_c8 & 15)]) = uv;
  }
  __syncthreads();

  // ---- main loop ----
#pragma unroll 2
  for (int t = 0; t < NSTEP; ++t) {
    const int cur = t & 1, nxt = cur ^ 1;

    if (t < NSTEP - 1) {
      if (tid < 512) {                      // issue A loads early (HBM latency)
        av0 = *(const float4*)(xrow + (t + 1) * BK);
        av1 = *(const float4*)(xrow + (t + 1) * BK + 4);
      }
#pragma unroll
      for (int i = 0; i < 4; ++i)           // B: linear async copy (pre-swizzled src)
        gload_lds16(Wq + (t + 1) * (HN * BK) + i * 12288 + tid * 16,
                    &Bs[nxt][i * 12288 + wv * 1024]);
    }

    // fragments from current buffers (swizzled reads)
    i32x4 afr[2][2], bfr[2][2];
#pragma unroll
    for (int kk = 0; kk < 2; ++kk) {
#pragma unroll
      for (int mi = 0; mi < 2; ++mi) {
        int r = mi * 32 + rr;
        int off = r * 64 + (((kk * 2 + kh) ^ ((r >> 1) & 3)) << 4);
        afr[mi][kk] = *(const i32x4*)(&As[cur][off]);
      }
#pragma unroll
      for (int ni = 0; ni < 2; ++ni) {
        int r = wv * 64 + ni * 32 + rr;
        int off = r * 64 + (((kk * 2 + kh) ^ ((r >> 1) & 3)) << 4);
        bfr[ni][kk] = *(const i32x4*)(&Bs[cur][off]);
      }
    }
#pragma unroll
    for (int kk = 0; kk < 2; ++kk)
#pragma unroll
      for (int mi = 0; mi < 2; ++mi)
#pragma unroll
        for (int ni = 0; ni < 2; ++ni)
          acc[mi][ni] = __builtin_amdgcn_mfma_i32_32x32x32_i8(
              afr[mi][kk], bfr[ni][kk], acc[mi][ni], 0, 0, 0);

    if (t < NSTEP - 1 && tid < 512) {       // write A(t+1) late (T14 split)
      float f[8] = {av0.x, av0.y, av0.z, av0.w, av1.x, av1.y, av1.z, av1.w};
      uint32_t b[8];
#pragma unroll
      for (int j = 0; j < 8; ++j) {
        int q = (int)rintf((f[j] - 0.5f) * 254.0f);
        q = q < -128 ? -128 : (q > 127 ? 127 : q);
        b[j] = (uint32_t)q & 0xff;
      }
      uint2 uv;
      uv.x = b[0] | (b[1] << 8) | (b[2] << 16) | (b[3] << 24);
      uv.y = b[4] | (b[5] << 8) | (b[6] << 16) | (b[7] << 24);
      int chunk = (ar_c8 >> 4) ^ ((ar_row >> 1) & 3);
      *(uint2*)(&As[nxt][ar_row * 64 + chunk * 16 + (ar_c8 & 15)]) = uv;
    }
    __syncthreads();
  }

  // ---- epilogue: out = acc * (w_scale/127) + pos_emb ----
  const float cscale = (__uint_as_float(*wmaxbits) / 127.0f) * (1.0f / 127.0f);
  const int p0 = m0 - (m0 / PP) * PP;       // m0 % P (tile never crosses batch)
#pragma unroll
  for (int mi = 0; mi < 2; ++mi) {
#pragma unroll
    for (int ni = 0; ni < 2; ++ni) {
      const int h = wv * 64 + ni * 32 + rr;
#pragma unroll
      for (int r16 = 0; r16 < 16; ++r16) {
        int rowoff = (r16 & 3) + ((r16 >> 2) << 3) + (kh << 2);
        int m = m0 + mi * 32 + rowoff;
        int p = p0 + mi * 32 + rowoff;
        out[m * HN + h] = (float)acc[mi][ni][r16] * cscale + pos[p * HN + h];
      }
    }
  }
}

// ---------------------------------------------------------------------------
extern "C" void kernel_launch(void* const* d_in, const int* in_sizes, int n_in,
                              void* d_out, int out_size, void* d_ws, size_t ws_size,
                              hipStream_t stream) {
  const float* X   = (const float*)d_in[0];   // pixel_values [16,9216,768]
  const float* W   = (const float*)d_in[1];   // proj_weight  [768,768]
  const float* pos = (const float*)d_in[2];   // pos_emb      [9216,768]
  float* out = (float*)d_out;

  uint32_t* wmaxbits = (uint32_t*)d_ws;
  int8_t*   wq       = (int8_t*)d_ws + 256;   // 589824 B swizzled int8 image

  hipMemsetAsync(d_ws, 0, 4, stream);
  wmax_kernel<<<576, 256, 0, stream>>>(W, wmaxbits);
  wq_kernel<<<576, 256, 0, stream>>>(W, wmaxbits, (int32_t*)wq);
  gemm_kernel<<<M_TOT / BM, THREADS, 0, stream>>>(X, wq, wmaxbits, pos, out);
}

// Round 3
// 838.178 us; speedup vs baseline: 1.0258x; 1.0258x over previous
//
#include <hip/hip_runtime.h>
#include <stdint.h>

// Problem constants
#define M_TOT 147456   // B*P = 16*9216
#define KD    768      // D (= K of GEMM)
#define HN    768      // H (= N of GEMM)
#define PP    9216
#define BM    32       // rows per block
#define NKC   48       // 16-byte chunks along K (768/16)
#define THREADS 512    // 8 waves

typedef __attribute__((ext_vector_type(4)))  int i32x4;
typedef __attribute__((ext_vector_type(16))) int i32x16;

// ---------------------------------------------------------------------------
// Kernel 0: max |W| -> ws[0] (uint bits; valid compare for non-negative floats)
__global__ void wmax_kernel(const float* __restrict__ w, uint32_t* __restrict__ wmax) {
  int i = blockIdx.x * blockDim.x + threadIdx.x;
  const float4* w4 = (const float4*)w;
  const int n4 = (HN * KD) / 4;           // 147456
  float m = 0.0f;
  for (int j = i; j < n4; j += gridDim.x * blockDim.x) {
    float4 v = w4[j];
    m = fmaxf(m, fmaxf(fmaxf(fabsf(v.x), fabsf(v.y)), fmaxf(fabsf(v.z), fabsf(v.w))));
  }
  for (int off = 32; off; off >>= 1) m = fmaxf(m, __shfl_xor(m, off, 64));
  if ((threadIdx.x & 63) == 0) atomicMax(wmax, __float_as_uint(m));
}

// ---------------------------------------------------------------------------
// Kernel 1: quantize W -> int8 in MFMA B-fragment layout:
//   chunk ci = kc*768 + h  holds  W_q[h][kc*16 .. kc*16+15]  (16 bytes).
// A wave's B-fragment load (col h, k-chunk kc) is one global_load_dwordx4 at
// (kc*768+h)*16 — 512 B contiguous per half-wave, L2-resident (576 KB total).
__global__ void wq_kernel(const float* __restrict__ w,
                          const uint32_t* __restrict__ wmaxbits,
                          uint32_t* __restrict__ wt) {
  int ci = blockIdx.x * blockDim.x + threadIdx.x;     // one 16B chunk each
  if (ci >= HN * NKC) return;
  const float s = __uint_as_float(*wmaxbits) / 127.0f;
  const int h  = ci % HN;
  const int kc = ci / HN;
  const float* src = w + h * KD + kc * 16;
  uint32_t words[4];
#pragma unroll
  for (int g = 0; g < 4; ++g) {
    float4 v = *(const float4*)(src + 4 * g);
    int q0 = (int)rintf(v.x / s); q0 = q0 < -128 ? -128 : (q0 > 127 ? 127 : q0);
    int q1 = (int)rintf(v.y / s); q1 = q1 < -128 ? -128 : (q1 > 127 ? 127 : q1);
    int q2 = (int)rintf(v.z / s); q2 = q2 < -128 ? -128 : (q2 > 127 ? 127 : q2);
    int q3 = (int)rintf(v.w / s); q3 = q3 < -128 ? -128 : (q3 > 127 ? 127 : q3);
    words[g] = ((uint32_t)q0 & 0xff) | (((uint32_t)q1 & 0xff) << 8) |
               (((uint32_t)q2 & 0xff) << 16) | (((uint32_t)q3 & 0xff) << 24);
  }
  uint32_t* dst = wt + (size_t)ci * 4;
  dst[0] = words[0]; dst[1] = words[1]; dst[2] = words[2]; dst[3] = words[3];
}

// ---------------------------------------------------------------------------
// Kernel 2: fused GEMM. 8 waves, wave-tile 32x96 (1x3 of 32x32x32 i8 MFMA).
// A: staged once to LDS (quantized int8, 24 KB, swizzled; ONE barrier/block).
// B: direct from L2-resident Wt, 2-deep register pipeline.
__global__ __launch_bounds__(THREADS, 4) void gemm_kernel(
    const float* __restrict__ X, const i32x4* __restrict__ Wt,
    const uint32_t* __restrict__ wmaxbits, const float* __restrict__ pos,
    float* __restrict__ out) {
  // A tile: byte (row,k): row*768 + slot(kc,row)*16 + (k&15),
  // slot = (kc&~7) | ((kc&7)^(row&7)) -> read phases uniform over 8 bank-phases.
  __shared__ __align__(16) signed char As[BM * KD];   // 24 KB

  const int tid  = threadIdx.x;
  const int lane = tid & 63;
  const int wv   = tid >> 6;          // 0..7: cols [wv*96, wv*96+96)
  const int rr   = lane & 31;
  const int kh   = lane >> 5;
  const int m0   = blockIdx.x * BM;

  // ---- stage A: coalesced float4 reads, quantize, swizzled LDS writes ----
  const float4* xsrc = (const float4*)(X + (size_t)m0 * KD);
#pragma unroll
  for (int half = 0; half < 2; ++half) {
    float4 v[6];
#pragma unroll
    for (int j = 0; j < 6; ++j) v[j] = xsrc[tid + 512 * (6 * half + j)];
#pragma unroll
    for (int j = 0; j < 6; ++j) {
      const int idx  = tid + 512 * (6 * half + j);   // float4 index in 32x768 tile
      const int row  = idx / 192;
      const int r192 = idx - row * 192;
      const int kc   = r192 >> 2;
      const int wrd  = r192 & 3;
      uint32_t p;
      p  = ((uint32_t)((int)rintf((v[j].x - 0.5f) * 254.0f)) & 255u);
      p |= ((uint32_t)((int)rintf((v[j].y - 0.5f) * 254.0f)) & 255u) << 8;
      p |= ((uint32_t)((int)rintf((v[j].z - 0.5f) * 254.0f)) & 255u) << 16;
      p |= ((uint32_t)((int)rintf((v[j].w - 0.5f) * 254.0f)) & 255u) << 24;
      const int slot = (kc & ~7) | ((kc & 7) ^ (row & 7));
      *(uint32_t*)(&As[row * KD + slot * 16 + wrd * 4]) = p;
    }
  }
  __syncthreads();                      // the block's ONLY barrier

  // ---- accumulators ----
  i32x16 acc[3];
#pragma unroll
  for (int ni = 0; ni < 3; ++ni)
#pragma unroll
    for (int r = 0; r < 16; ++r) acc[ni][r] = 0;

  const i32x4* bbase = Wt + (size_t)kh * HN + (size_t)wv * 96 + rr;
  const signed char* arow = As + rr * KD;

  // ---- K loop: 24 steps of k=32, 2-deep register pipeline ----
  i32x4 afr[2];
  i32x4 bfr[2][3];
#pragma unroll
  for (int s = 0; s < 2; ++s) {
    const i32x4* bp = bbase + (size_t)(2 * s) * HN;
    bfr[s][0] = bp[0];
    bfr[s][1] = bp[32];
    bfr[s][2] = bp[64];
    const int c = 2 * s + kh;
    const int slot = (c & ~7) | ((c & 7) ^ (rr & 7));
    afr[s] = *(const i32x4*)(arow + slot * 16);
  }

#pragma unroll
  for (int s = 0; s < 24; ++s) {
    const int cur = s & 1;
    acc[0] = __builtin_amdgcn_mfma_i32_32x32x32_i8(afr[cur], bfr[cur][0], acc[0], 0, 0, 0);
    acc[1] = __builtin_amdgcn_mfma_i32_32x32x32_i8(afr[cur], bfr[cur][1], acc[1], 0, 0, 0);
    acc[2] = __builtin_amdgcn_mfma_i32_32x32x32_i8(afr[cur], bfr[cur][2], acc[2], 0, 0, 0);
    if (s + 2 < 24) {
      const i32x4* bp = bbase + (size_t)(2 * (s + 2)) * HN;
      bfr[cur][0] = bp[0];
      bfr[cur][1] = bp[32];
      bfr[cur][2] = bp[64];
      const int c = 2 * (s + 2) + kh;
      const int slot = (c & ~7) | ((c & 7) ^ (rr & 7));
      afr[cur] = *(const i32x4*)(arow + slot * 16);
    }
  }

  // ---- epilogue: out = acc * (w_scale/127) + pos_emb ----
  const float cscale = (__uint_as_float(*wmaxbits) / 127.0f) * (1.0f / 127.0f);
  const int p0 = m0 - (m0 / PP) * PP;   // m0 % P (BM divides P: never crosses batch)
#pragma unroll
  for (int ni = 0; ni < 3; ++ni) {
    const int h = wv * 96 + ni * 32 + rr;
#pragma unroll
    for (int r16 = 0; r16 < 16; ++r16) {
      const int rowoff = (r16 & 3) + ((r16 >> 2) << 3) + (kh << 2);
      out[(size_t)(m0 + rowoff) * HN + h] =
          (float)acc[ni][r16] * cscale + pos[(size_t)(p0 + rowoff) * HN + h];
    }
  }
}

// ---------------------------------------------------------------------------
extern "C" void kernel_launch(void* const* d_in, const int* in_sizes, int n_in,
                              void* d_out, int out_size, void* d_ws, size_t ws_size,
                              hipStream_t stream) {
  const float* X   = (const float*)d_in[0];   // pixel_values [16,9216,768]
  const float* W   = (const float*)d_in[1];   // proj_weight  [768,768]
  const float* pos = (const float*)d_in[2];   // pos_emb      [9216,768]
  float* out = (float*)d_out;

  uint32_t* wmaxbits = (uint32_t*)d_ws;
  uint32_t* wt       = (uint32_t*)((char*)d_ws + 256);  // 589824 B fragment image

  hipMemsetAsync(d_ws, 0, 4, stream);
  wmax_kernel<<<576, 256, 0, stream>>>(W, wmaxbits);
  wq_kernel<<<(HN * NKC + 255) / 256, 256, 0, stream>>>(W, wmaxbits, wt);
  gemm_kernel<<<M_TOT / BM, THREADS, 0, stream>>>(X, (const i32x4*)wt, wmaxbits, pos, out);
}